// Round 1
// baseline (1452.840 us; speedup 1.0000x reference)
//
#include <hip/hip_runtime.h>
#include <hip/hip_bf16.h>
#include <math.h>

// Problem constants (match reference setup_inputs)
#define BB 64
#define NN 900
#define CC 365
#define MM 64
#define KK 64
#define EPSV 1e-6f

// ---------------------------------------------------------------------------
// Kernel A: cost matrix. One wave (64 lanes) per (b, n) row.
//   cost[b,n,m] = -softmax(logits[b,n,:])[label[b,m]]
//               + 5 * L1(pred_box[b,n], tgt_box[b,m])
//               - 2 * GIoU(pred_box[b,n], tgt_box[b,m])
// ---------------------------------------------------------------------------
__global__ __launch_bounds__(256) void cost_kernel(
    const float* __restrict__ logits,   // [B,N,C]
    const float* __restrict__ pboxes,   // [B,N,4] cxcywh
    const int*   __restrict__ labels,   // [B,M]
    const float* __restrict__ tboxes,   // [B,M,4] cxcywh
    float* __restrict__ cost)           // [B,N,M]
{
    const int wid  = (blockIdx.x * blockDim.x + threadIdx.x) >> 6;  // row id
    const int lane = threadIdx.x & 63;
    if (wid >= BB * NN) return;
    const int b = wid / NN;

    // --- softmax reduction over C=365 logits, strided across 64 lanes ---
    const float* lrow = logits + (size_t)wid * CC;
    float reg[6];
#pragma unroll
    for (int i = 0; i < 6; ++i) {
        int idx = lane + i * 64;
        reg[i] = (idx < CC) ? lrow[idx] : -INFINITY;
    }
    float mx = reg[0];
#pragma unroll
    for (int i = 1; i < 6; ++i) mx = fmaxf(mx, reg[i]);
#pragma unroll
    for (int off = 32; off; off >>= 1) mx = fmaxf(mx, __shfl_xor(mx, off));

    float se = 0.0f;
#pragma unroll
    for (int i = 0; i < 6; ++i) se += expf(reg[i] - mx);  // expf(-inf)=0
#pragma unroll
    for (int off = 32; off; off >>= 1) se += __shfl_xor(se, off);

    // --- gather logit at this lane's target label via bpermute ---
    const int L    = labels[b * MM + lane];       // 0..C-1
    const int srcl = L & 63;
    const int ri   = L >> 6;
    float g0 = __shfl(reg[0], srcl);
    float g1 = __shfl(reg[1], srcl);
    float g2 = __shfl(reg[2], srcl);
    float g3 = __shfl(reg[3], srcl);
    float g4 = __shfl(reg[4], srcl);
    float g5 = __shfl(reg[5], srcl);
    float gl = g0;
    gl = (ri == 1) ? g1 : gl;
    gl = (ri == 2) ? g2 : gl;
    gl = (ri == 3) ? g3 : gl;
    gl = (ri == 4) ? g4 : gl;
    gl = (ri == 5) ? g5 : gl;
    const float prob   = expf(gl - mx) / se;
    const float cclass = -prob;

    // --- box costs: lane m handles target m ---
    const float4 pb = *(const float4*)(pboxes + (size_t)wid * 4);          // broadcast
    const float4 tb = *(const float4*)(tboxes + ((size_t)b * MM + lane) * 4);

    const float l1 = fabsf(pb.x - tb.x) + fabsf(pb.y - tb.y) +
                     fabsf(pb.z - tb.z) + fabsf(pb.w - tb.w);

    // cxcywh -> xyxy
    const float px0 = pb.x - 0.5f * pb.z, py0 = pb.y - 0.5f * pb.w;
    const float px1 = pb.x + 0.5f * pb.z, py1 = pb.y + 0.5f * pb.w;
    const float tx0 = tb.x - 0.5f * tb.z, ty0 = tb.y - 0.5f * tb.w;
    const float tx1 = tb.x + 0.5f * tb.z, ty1 = tb.y + 0.5f * tb.w;

    const float ltx = fmaxf(px0, tx0), lty = fmaxf(py0, ty0);
    const float rbx = fminf(px1, tx1), rby = fminf(py1, ty1);
    const float iw = fmaxf(rbx - ltx, 0.0f), ih = fmaxf(rby - lty, 0.0f);
    const float inter = iw * ih;
    const float a1 = (px1 - px0) * (py1 - py0);
    const float a2 = (tx1 - tx0) * (ty1 - ty0);
    const float uni = a1 + a2 - inter;
    const float iou = inter / (uni + EPSV);
    const float ex0 = fminf(px0, tx0), ey0 = fminf(py0, ty0);
    const float ex1 = fmaxf(px1, tx1), ey1 = fmaxf(py1, ty1);
    const float ae = (ex1 - ex0) * (ey1 - ey0);
    const float giou = iou - (ae - uni) / (ae + EPSV);

    const float c = 1.0f * cclass + 5.0f * l1 + 2.0f * (-giou);
    cost[(size_t)wid * MM + lane] = c;
}

// ---------------------------------------------------------------------------
// Kernel B: greedy assignment, one block (256 thr) per batch.
// Maintains per-row (min value, argmin col) cache in LDS; each of K=64 steps
// does a block argmin over 900 packed keys and rescans only rows whose cached
// argmin column was just removed. Key = (order-mapped f32 << 10) | row, so
// u64-min == lexicographic (val, row) min; within-row first-col tie-break is
// preserved by the strict-< sequential scan. This matches jnp.argmin's
// first-flat-index tie-break exactly.
// ---------------------------------------------------------------------------
#define MAXKEY 0xFFFFFFFFFFFFFFFFull

__device__ __forceinline__ unsigned long long packkey(float v, int r) {
    unsigned u = __float_as_uint(v);
    u = (u & 0x80000000u) ? ~u : (u | 0x80000000u);  // order-preserving map
    return ((unsigned long long)u << 10) | (unsigned)r;
}

__global__ __launch_bounds__(256) void greedy_kernel(
    const float* __restrict__ cost,  // [B,N,M]
    float* __restrict__ outP,        // [B,K]
    float* __restrict__ outT)        // [B,K]
{
    const int b   = blockIdx.x;
    const int tid = threadIdx.x;
    const float* cb = cost + (size_t)b * NN * MM;

    __shared__ unsigned long long keys[NN];
    __shared__ unsigned short rowarg[NN];
    __shared__ int colmask[MM];
    __shared__ int selP[KK], selT[KK];
    __shared__ unsigned long long wred[4];
    __shared__ int bti;

    if (tid < MM) colmask[tid] = 0;

    // Phase 1: per-row min/argmin (strict < keeps first occurrence)
    for (int r = tid; r < NN; r += 256) {
        const float* row = cb + r * MM;
        float best = INFINITY;
        int barg = 0;
#pragma unroll
        for (int j = 0; j < MM; j += 4) {
            float4 v = *(const float4*)(row + j);
            if (v.x < best) { best = v.x; barg = j; }
            if (v.y < best) { best = v.y; barg = j + 1; }
            if (v.z < best) { best = v.z; barg = j + 2; }
            if (v.w < best) { best = v.w; barg = j + 3; }
        }
        keys[r] = packkey(best, r);
        rowarg[r] = (unsigned short)barg;
    }
    __syncthreads();

    for (int it = 0; it < KK; ++it) {
        // block argmin over keys
        unsigned long long k0 = MAXKEY;
        for (int r = tid; r < NN; r += 256) {
            unsigned long long kv = keys[r];
            if (kv < k0) k0 = kv;
        }
#pragma unroll
        for (int off = 32; off; off >>= 1) {
            unsigned long long o = __shfl_down(k0, off);
            if (o < k0) k0 = o;
        }
        if ((tid & 63) == 0) wred[tid >> 6] = k0;
        __syncthreads();
        if (tid == 0) {
            unsigned long long kk = wred[0];
            if (wred[1] < kk) kk = wred[1];
            if (wred[2] < kk) kk = wred[2];
            if (wred[3] < kk) kk = wred[3];
            const int pi = (int)(kk & 1023u);
            const int ti = rowarg[pi];
            selP[it] = pi;
            selT[it] = ti;
            keys[pi] = MAXKEY;   // row assigned
            colmask[ti] = 1;     // col assigned
            bti = ti;
        }
        __syncthreads();
        // rescan rows whose cached argmin column was removed
        const int ti = bti;
        for (int r = tid; r < NN; r += 256) {
            if (keys[r] != MAXKEY && rowarg[r] == (unsigned short)ti) {
                const float* row = cb + r * MM;
                float best = INFINITY;
                int barg = -1;
#pragma unroll 4
                for (int j = 0; j < MM; ++j) {
                    if (!colmask[j]) {
                        float v = row[j];
                        if (v < best) { best = v; barg = j; }
                    }
                }
                if (barg < 0) {
                    keys[r] = MAXKEY;
                    rowarg[r] = 0;
                } else {
                    keys[r] = packkey(best, r);
                    rowarg[r] = (unsigned short)barg;
                }
            }
        }
        __syncthreads();
    }

    // write indices (as float — harness treats non-bf16 outputs as float32)
    if (tid < KK) {
        outP[b * KK + tid] = (float)selP[tid];
        outT[b * KK + tid] = (float)selT[tid];
    }
}

// ---------------------------------------------------------------------------
extern "C" void kernel_launch(void* const* d_in, const int* in_sizes, int n_in,
                              void* d_out, int out_size, void* d_ws, size_t ws_size,
                              hipStream_t stream) {
    const float* pred_logits = (const float*)d_in[0];  // [64,900,365]
    const float* pred_boxes  = (const float*)d_in[1];  // [64,900,4]
    const int*   tgt_labels  = (const int*)d_in[2];    // [64,64]
    const float* tgt_boxes   = (const float*)d_in[3];  // [64,64,4]

    float* cost = (float*)d_out;                       // [64,900,64]
    float* outP = cost + (size_t)BB * NN * MM;         // [64,64]
    float* outT = outP + (size_t)BB * KK;              // [64,64]

    // Kernel A: 57600 rows, one wave each, 4 waves per block
    const int nrows = BB * NN;
    const int blocksA = (nrows + 3) / 4;  // 14400
    cost_kernel<<<blocksA, 256, 0, stream>>>(pred_logits, pred_boxes,
                                             tgt_labels, tgt_boxes, cost);

    // Kernel B: one block per batch
    greedy_kernel<<<BB, 256, 0, stream>>>(cost, outP, outT);
}

// Round 2
// 595.895 us; speedup vs baseline: 2.4381x; 2.4381x over previous
//
#include <hip/hip_runtime.h>
#include <hip/hip_bf16.h>
#include <math.h>

// Problem constants (match reference setup_inputs)
#define BB 64
#define NN 900
#define CC 365
#define MM 64
#define KK 64
#define EPSV 1e-6f
#define RPL 15            // rows per lane: 60 lanes * 15 = 900
#define NPAD 960
#define UMAX 0xFFFFFFFFu

// order-preserving f32 -> u32 map (monotone, injective; never produces UMAX
// for finite inputs, so UMAX is a safe "row removed" marker)
__device__ __forceinline__ unsigned omap(float v) {
    unsigned u = __float_as_uint(v);
    return (u & 0x80000000u) ? ~u : (u | 0x80000000u);
}

// ---------------------------------------------------------------------------
// Kernel A: cost matrix. One wave per (b, n) row.
// ---------------------------------------------------------------------------
__global__ __launch_bounds__(256) void cost_kernel(
    const float* __restrict__ logits,   // [B,N,C]
    const float* __restrict__ pboxes,   // [B,N,4] cxcywh
    const int*   __restrict__ labels,   // [B,M]
    const float* __restrict__ tboxes,   // [B,M,4] cxcywh
    float* __restrict__ cost)           // [B,N,M]
{
    const int wid  = (blockIdx.x * blockDim.x + threadIdx.x) >> 6;
    const int lane = threadIdx.x & 63;
    if (wid >= BB * NN) return;
    const int b = wid / NN;

    const float* lrow = logits + (size_t)wid * CC;
    const int L = labels[b * MM + lane];
    const float gl = lrow[L];   // direct gather; row is L1/L2-hot from the strided loads

    float reg[6];
#pragma unroll
    for (int i = 0; i < 6; ++i) {
        int idx = lane + i * 64;
        reg[i] = (idx < CC) ? lrow[idx] : -INFINITY;
    }
    float mx = reg[0];
#pragma unroll
    for (int i = 1; i < 6; ++i) mx = fmaxf(mx, reg[i]);
#pragma unroll
    for (int off = 32; off; off >>= 1) mx = fmaxf(mx, __shfl_xor(mx, off));

    float se = 0.0f;
#pragma unroll
    for (int i = 0; i < 6; ++i) se += expf(reg[i] - mx);  // expf(-inf)=0
#pragma unroll
    for (int off = 32; off; off >>= 1) se += __shfl_xor(se, off);

    const float cclass = -(expf(gl - mx) / se);

    // --- box costs: lane m handles target m (identical math to passing v1) ---
    const float4 pb = *(const float4*)(pboxes + (size_t)wid * 4);
    const float4 tb = *(const float4*)(tboxes + ((size_t)b * MM + lane) * 4);

    const float l1 = fabsf(pb.x - tb.x) + fabsf(pb.y - tb.y) +
                     fabsf(pb.z - tb.z) + fabsf(pb.w - tb.w);

    const float px0 = pb.x - 0.5f * pb.z, py0 = pb.y - 0.5f * pb.w;
    const float px1 = pb.x + 0.5f * pb.z, py1 = pb.y + 0.5f * pb.w;
    const float tx0 = tb.x - 0.5f * tb.z, ty0 = tb.y - 0.5f * tb.w;
    const float tx1 = tb.x + 0.5f * tb.z, ty1 = tb.y + 0.5f * tb.w;

    const float ltx = fmaxf(px0, tx0), lty = fmaxf(py0, ty0);
    const float rbx = fminf(px1, tx1), rby = fminf(py1, ty1);
    const float iw = fmaxf(rbx - ltx, 0.0f), ih = fmaxf(rby - lty, 0.0f);
    const float inter = iw * ih;
    const float a1 = (px1 - px0) * (py1 - py0);
    const float a2 = (tx1 - tx0) * (ty1 - ty0);
    const float uni = a1 + a2 - inter;
    const float iou = inter / (uni + EPSV);
    const float ex0 = fminf(px0, tx0), ey0 = fminf(py0, ty0);
    const float ex1 = fmaxf(px1, tx1), ey1 = fmaxf(py1, ty1);
    const float ae = (ex1 - ex0) * (ey1 - ey0);
    const float giou = iou - (ae - uni) / (ae + EPSV);

    const float c = 1.0f * cclass + 5.0f * l1 + 2.0f * (-giou);
    cost[(size_t)wid * MM + lane] = c;
}

// ---------------------------------------------------------------------------
// Kernel B: greedy assignment. One block/batch: 4-wave phase-1 (per-row argmin
// into LDS), then wave 0 alone runs the 64 selection iterations with all state
// in registers (no LDS, no barriers in the loop).
//
// Ownership: lane L owns rows [15L, 15L+15). Lane order + within-lane slot
// order == global row order, so (value asc, lane asc via ballot-ffs, slot asc
// via strict-< chain) == jnp.argmin's first-flat-index tie-break. Within-row
// first-col tie-break: strict-< sequential scan. Hard masking is equivalent to
// the reference's +1e9 soft mask (an unmasked entry always exists, K<=M).
// ---------------------------------------------------------------------------
__global__ __launch_bounds__(256) void greedy_kernel(
    const float* __restrict__ cost,  // [B,N,M]
    float* __restrict__ outP,        // [B,K]
    float* __restrict__ outT)        // [B,K]
{
    const int b   = blockIdx.x;
    const int tid = threadIdx.x;
    const float* cb = cost + (size_t)b * NN * MM;

    __shared__ unsigned keyS[NPAD];
    __shared__ unsigned colS[NPAD];

    // ---- Phase 1: per-row (minval, argcol), 256 threads ----
    for (int r = tid; r < NPAD; r += 256) {
        if (r < NN) {
            const float* row = cb + r * MM;
            float best = INFINITY; int bc = 0;
#pragma unroll
            for (int j = 0; j < MM; j += 4) {
                float4 v = *(const float4*)(row + j);
                if (v.x < best) { best = v.x; bc = j; }
                if (v.y < best) { best = v.y; bc = j + 1; }
                if (v.z < best) { best = v.z; bc = j + 2; }
                if (v.w < best) { best = v.w; bc = j + 3; }
            }
            keyS[r] = omap(best);
            colS[r] = (unsigned)bc;
        } else {
            keyS[r] = UMAX;   // pad rows: never selectable
            colS[r] = 63u;
        }
    }
    __syncthreads();
    if (tid >= 64) return;   // wave 0 continues alone; no barriers below

    const int lane = tid;
    const int base = lane * RPL;

    // per-lane state, all statically indexed (registers)
    unsigned vals[RPL];
    unsigned long long a0 = 0, a1 = 0;   // 6-bit argcols: a0 slots 0..9, a1 slots 10..14
#pragma unroll
    for (int i = 0; i < RPL; ++i) {
        vals[i] = keyS[base + i];
        unsigned long long c = (unsigned long long)(colS[base + i] & 63u);
        if (i < 10) a0 |= c << (6 * i);
        else        a1 |= c << (6 * (i - 10));
    }

    unsigned long long colbits = 0;
    int selp = 0, selt = 0;

#pragma unroll 1
    for (int it = 0; it < KK; ++it) {
        // lane-local argmin over 15 slots (strict < keeps lowest row)
        unsigned bv = UMAX; int bs = 0; unsigned bc = 0;
#pragma unroll
        for (int i = 0; i < RPL; ++i) {
            unsigned ci = (i < 10) ? (unsigned)(a0 >> (6 * i)) & 63u
                                   : (unsigned)(a1 >> (6 * (i - 10))) & 63u;
            if (vals[i] < bv) { bv = vals[i]; bs = i; bc = ci; }
        }
        // wave-wide min (value only)
        unsigned m = bv;
#pragma unroll
        for (int off = 32; off; off >>= 1) {
            unsigned o = (unsigned)__shfl_xor((int)m, off);
            m = (o < m) ? o : m;
        }
        // first-occurrence lane -> global (pi, ti)
        const unsigned long long eq = __ballot(bv == m);
        const int wl = __ffsll(eq) - 1;
        const int pi = __shfl(base + bs, wl);
        const int ti = __shfl((int)bc, wl);

        if (lane == it) { selp = pi; selt = ti; }
        colbits |= 1ull << ti;

        // invalidate winner slot (winner lane only; branchless static writes)
        {
            const bool w = (lane == wl);
#pragma unroll
            for (int i = 0; i < RPL; ++i)
                if (w && i == bs) vals[i] = UMAX;
        }

        // pending: my live rows whose cached argmin col was just removed
        unsigned pend = 0;
#pragma unroll
        for (int i = 0; i < RPL; ++i) {
            unsigned ci = (i < 10) ? (unsigned)(a0 >> (6 * i)) & 63u
                                   : (unsigned)(a1 >> (6 * (i - 10))) & 63u;
            if (vals[i] != UMAX && ci == (unsigned)ti) pend |= 1u << i;
        }

        const unsigned cl = (unsigned)colbits;
        const unsigned ch = (unsigned)(colbits >> 32);
#pragma unroll 1
        while (__any((int)pend)) {
            if (pend) {
                const int s = __ffs((int)pend) - 1;
                pend &= pend - 1;
                const float* row = cb + (base + s) * MM;
                float best = INFINITY; int bc2 = 0;
#pragma unroll
                for (int j = 0; j < MM; j += 4) {
                    float4 v = *(const float4*)(row + j);
                    const unsigned mw = (j < 32) ? cl : ch;
                    const int jb = j & 31;
                    const float vx = ((mw >> (jb + 0)) & 1u) ? INFINITY : v.x;
                    const float vy = ((mw >> (jb + 1)) & 1u) ? INFINITY : v.y;
                    const float vz = ((mw >> (jb + 2)) & 1u) ? INFINITY : v.z;
                    const float vw = ((mw >> (jb + 3)) & 1u) ? INFINITY : v.w;
                    if (vx < best) { best = vx; bc2 = j; }
                    if (vy < best) { best = vy; bc2 = j + 1; }
                    if (vz < best) { best = vz; bc2 = j + 2; }
                    if (vw < best) { best = vw; bc2 = j + 3; }
                }
                const unsigned nk = omap(best);
                const unsigned long long nc = (unsigned long long)bc2;
                // static-index writeback of slot s
#pragma unroll
                for (int i = 0; i < RPL; ++i)
                    if (i == s) vals[i] = nk;
                if (s < 10) {
                    const int sh = 6 * s;
                    a0 = (a0 & ~(63ull << sh)) | (nc << sh);
                } else {
                    const int sh = 6 * (s - 10);
                    a1 = (a1 & ~(63ull << sh)) | (nc << sh);
                }
            }
        }
    }

    outP[b * KK + lane] = (float)selp;
    outT[b * KK + lane] = (float)selt;
}

// ---------------------------------------------------------------------------
extern "C" void kernel_launch(void* const* d_in, const int* in_sizes, int n_in,
                              void* d_out, int out_size, void* d_ws, size_t ws_size,
                              hipStream_t stream) {
    const float* pred_logits = (const float*)d_in[0];  // [64,900,365]
    const float* pred_boxes  = (const float*)d_in[1];  // [64,900,4]
    const int*   tgt_labels  = (const int*)d_in[2];    // [64,64]
    const float* tgt_boxes   = (const float*)d_in[3];  // [64,64,4]

    float* cost = (float*)d_out;                       // [64,900,64]
    float* outP = cost + (size_t)BB * NN * MM;         // [64,64]
    float* outT = outP + (size_t)BB * KK;              // [64,64]

    const int nrows = BB * NN;
    const int blocksA = (nrows + 3) / 4;  // 4 waves/block
    cost_kernel<<<blocksA, 256, 0, stream>>>(pred_logits, pred_boxes,
                                             tgt_labels, tgt_boxes, cost);

    greedy_kernel<<<BB, 256, 0, stream>>>(cost, outP, outT);
}

// Round 5
// 190.060 us; speedup vs baseline: 7.6441x; 3.1353x over previous
//
#include <hip/hip_runtime.h>
#include <hip/hip_bf16.h>
#include <math.h>

// Problem constants (match reference setup_inputs)
#define BB 64
#define NN 900
#define CC 365
#define MM 64
#define KK 64
#define EPSV 1e-6f
#define NCHUNK 8
#define CHROWS 113              // ceil(900/8)
#define MAXKEY 0xFFFFFFFFFFFFFFFFull

// order-preserving f32 -> u32 map (monotone, injective; finite inputs give
// omap < 2^32, so packed keys < 2^42 and MAXKEY is a safe removal marker)
__device__ __forceinline__ unsigned omap(float v) {
    unsigned u = __float_as_uint(v);
    return (u & 0x80000000u) ? ~u : (u | 0x80000000u);
}
// key = (val asc, row asc); u64 min == lexicographic min
__device__ __forceinline__ unsigned long long packkey(float v, int r) {
    return ((unsigned long long)omap(v) << 10) | (unsigned)r;
}

// ---------------------------------------------------------------------------
// Kernel A: cost matrix. One wave per (b, n) row. (unchanged, passing)
// ---------------------------------------------------------------------------
__global__ __launch_bounds__(256) void cost_kernel(
    const float* __restrict__ logits,   // [B,N,C]
    const float* __restrict__ pboxes,   // [B,N,4] cxcywh
    const int*   __restrict__ labels,   // [B,M]
    const float* __restrict__ tboxes,   // [B,M,4] cxcywh
    float* __restrict__ cost)           // [B,N,M]
{
    const int wid  = (blockIdx.x * blockDim.x + threadIdx.x) >> 6;
    const int lane = threadIdx.x & 63;
    if (wid >= BB * NN) return;
    const int b = wid / NN;

    const float* lrow = logits + (size_t)wid * CC;
    const int L = labels[b * MM + lane];
    const float gl = lrow[L];

    float reg[6];
#pragma unroll
    for (int i = 0; i < 6; ++i) {
        int idx = lane + i * 64;
        reg[i] = (idx < CC) ? lrow[idx] : -INFINITY;
    }
    float mx = reg[0];
#pragma unroll
    for (int i = 1; i < 6; ++i) mx = fmaxf(mx, reg[i]);
#pragma unroll
    for (int off = 32; off; off >>= 1) mx = fmaxf(mx, __shfl_xor(mx, off));

    float se = 0.0f;
#pragma unroll
    for (int i = 0; i < 6; ++i) se += expf(reg[i] - mx);  // expf(-inf)=0
#pragma unroll
    for (int off = 32; off; off >>= 1) se += __shfl_xor(se, off);

    const float cclass = -(expf(gl - mx) / se);

    const float4 pb = *(const float4*)(pboxes + (size_t)wid * 4);
    const float4 tb = *(const float4*)(tboxes + ((size_t)b * MM + lane) * 4);

    const float l1 = fabsf(pb.x - tb.x) + fabsf(pb.y - tb.y) +
                     fabsf(pb.z - tb.z) + fabsf(pb.w - tb.w);

    const float px0 = pb.x - 0.5f * pb.z, py0 = pb.y - 0.5f * pb.w;
    const float px1 = pb.x + 0.5f * pb.z, py1 = pb.y + 0.5f * pb.w;
    const float tx0 = tb.x - 0.5f * tb.z, ty0 = tb.y - 0.5f * tb.w;
    const float tx1 = tb.x + 0.5f * tb.z, ty1 = tb.y + 0.5f * tb.w;

    const float ltx = fmaxf(px0, tx0), lty = fmaxf(py0, ty0);
    const float rbx = fminf(px1, tx1), rby = fminf(py1, ty1);
    const float iw = fmaxf(rbx - ltx, 0.0f), ih = fmaxf(rby - lty, 0.0f);
    const float inter = iw * ih;
    const float a1 = (px1 - px0) * (py1 - py0);
    const float a2 = (tx1 - tx0) * (ty1 - ty0);
    const float uni = a1 + a2 - inter;
    const float iou = inter / (uni + EPSV);
    const float ex0 = fminf(px0, tx0), ey0 = fminf(py0, ty0);
    const float ex1 = fmaxf(px1, tx1), ey1 = fmaxf(py1, ty1);
    const float ae = (ex1 - ex0) * (ey1 - ey0);
    const float giou = iou - (ae - uni) / (ae + EPSV);

    const float c = 1.0f * cclass + 5.0f * l1 + 2.0f * (-giou);
    cost[(size_t)wid * MM + lane] = c;
}

// ---------------------------------------------------------------------------
// Kernel B1: per-column partial mins. Grid (8 chunks, 64 batches), 256 thr.
// Thread (wg, m) strides rows of its chunk; fully coalesced (consecutive tid
// -> consecutive m). Writes u64 keys to ws[b][chunk][m]  (64*8*64*8B = 256KB).
// ---------------------------------------------------------------------------
__global__ __launch_bounds__(256) void colmin_init_kernel(
    const float* __restrict__ cost,            // [B,N,M]
    unsigned long long* __restrict__ ws)       // [B,NCHUNK,M]
{
    const int ch = blockIdx.x;
    const int b  = blockIdx.y;
    const int m  = threadIdx.x & 63;
    const int wg = threadIdx.x >> 6;
    const float* cb = cost + (size_t)b * NN * MM;

    const int r0 = ch * CHROWS;
    const int r1 = (r0 + CHROWS < NN) ? r0 + CHROWS : NN;

    unsigned long long best = MAXKEY;
    for (int r = r0 + wg; r < r1; r += 4) {
        unsigned long long k = packkey(cb[r * MM + m], r);
        best = (k < best) ? k : best;
    }

    __shared__ unsigned long long part[4][MM];
    part[wg][m] = best;
    __syncthreads();
    if (threadIdx.x < MM) {
        unsigned long long k0 = part[0][threadIdx.x];
        unsigned long long k1 = part[1][threadIdx.x];
        unsigned long long k2 = part[2][threadIdx.x];
        unsigned long long k3 = part[3][threadIdx.x];
        k0 = (k1 < k0) ? k1 : k0;
        k2 = (k3 < k2) ? k3 : k2;
        k0 = (k2 < k0) ? k2 : k0;
        ws[((size_t)b * NCHUNK + ch) * MM + threadIdx.x] = k0;
    }
}

// ---------------------------------------------------------------------------
// Kernel B2: greedy selection, one wave per batch. Lane m owns column m's
// cached (min val, argmin row) key. Column removal = kill lane's key (free).
// Row removal invalidates a column cache with prob ~1/live_rows -> expected
// ~5 cooperative rescans total per batch. Invariant: every live column's key
// is the true min over live rows, so the wave-min of keys is the global min.
// Tie-break = (val asc, row asc via packed key, col asc via ballot+ffs) ==
// jnp.argmin first-flat-index. Hard masking == reference's +1e9 soft mask.
// Row liveness: lane l keeps a 15-bit register bitmap for rows r == l (mod 64).
// ---------------------------------------------------------------------------
__global__ __launch_bounds__(64) void greedy_kernel(
    const float* __restrict__ cost,                  // [B,N,M]
    const unsigned long long* __restrict__ ws,       // [B,NCHUNK,M]
    float* __restrict__ outP,                        // [B,K]
    float* __restrict__ outT)                        // [B,K]
{
    const int b    = blockIdx.x;
    const int lane = threadIdx.x;       // == column index
    const float* cb = cost + (size_t)b * NN * MM;

    unsigned long long mykey = MAXKEY;
#pragma unroll
    for (int ch = 0; ch < NCHUNK; ++ch) {
        unsigned long long k = ws[((size_t)b * NCHUNK + ch) * MM + lane];
        mykey = (k < mykey) ? k : mykey;
    }

    unsigned deadbits = 0;              // rows l+64j removed, bit j
    int selp = 0, selt = 0;

#pragma unroll 1
    for (int it = 0; it < KK; ++it) {
        // wave-wide u64 min of live column keys
        unsigned long long mn = mykey;
#pragma unroll
        for (int off = 32; off; off >>= 1) {
            unsigned long long o = __shfl_xor(mn, off);
            mn = (o < mn) ? o : mn;
        }
        const unsigned long long eq = __ballot(mykey == mn);
        const int c = __ffsll((long long)eq) - 1;   // smallest col among ties
        const int r = (int)(mn & 1023u);

        if (lane == it) { selp = r; selt = c; }
        if (lane == c) mykey = MAXKEY;                      // column removed
        if (lane == (r & 63)) deadbits |= 1u << (r >> 6);   // row removed

        // live columns whose cached argmin row was just removed (rare)
        unsigned long long pend =
            __ballot(mykey != MAXKEY && (int)(mykey & 1023u) == r);
#pragma unroll 1
        while (pend) {
            const int pc = __ffsll((long long)pend) - 1;
            pend &= pend - 1;
            // all 64 lanes cooperate: lane covers rows lane+64j
            unsigned long long best = MAXKEY;
#pragma unroll
            for (int j = 0; j < 15; ++j) {
                const int rr = lane + 64 * j;
                if (rr < NN && !((deadbits >> j) & 1u)) {
                    unsigned long long k = packkey(cb[rr * MM + pc], rr);
                    best = (k < best) ? k : best;
                }
            }
#pragma unroll
            for (int off = 32; off; off >>= 1) {
                unsigned long long o = __shfl_xor(best, off);
                best = (o < best) ? o : best;
            }
            if (lane == pc) mykey = best;   // >=1 live row always remains
        }
    }

    outP[b * KK + lane] = (float)selp;
    outT[b * KK + lane] = (float)selt;
}

// ---------------------------------------------------------------------------
extern "C" void kernel_launch(void* const* d_in, const int* in_sizes, int n_in,
                              void* d_out, int out_size, void* d_ws, size_t ws_size,
                              hipStream_t stream) {
    const float* pred_logits = (const float*)d_in[0];  // [64,900,365]
    const float* pred_boxes  = (const float*)d_in[1];  // [64,900,4]
    const int*   tgt_labels  = (const int*)d_in[2];    // [64,64]
    const float* tgt_boxes   = (const float*)d_in[3];  // [64,64,4]

    float* cost = (float*)d_out;                       // [64,900,64]
    float* outP = cost + (size_t)BB * NN * MM;         // [64,64]
    float* outT = outP + (size_t)BB * KK;              // [64,64]
    unsigned long long* wskeys = (unsigned long long*)d_ws;  // 256 KB needed

    const int nrows = BB * NN;
    const int blocksA = (nrows + 3) / 4;  // 4 waves/block
    cost_kernel<<<blocksA, 256, 0, stream>>>(pred_logits, pred_boxes,
                                             tgt_labels, tgt_boxes, cost);

    colmin_init_kernel<<<dim3(NCHUNK, BB), 256, 0, stream>>>(cost, wskeys);

    greedy_kernel<<<BB, 64, 0, stream>>>(cost, wskeys, outP, outT);
}

// Round 12
// 187.839 us; speedup vs baseline: 7.7345x; 1.0118x over previous
//
#include <hip/hip_runtime.h>
#include <hip/hip_bf16.h>
#include <math.h>

// Problem constants (match reference setup_inputs)
#define BB 64
#define NN 900
#define CC 365
#define MM 64
#define KK 64
#define EPSV 1e-6f
#define MAXKEY 0xFFFFFFFFFFFFFFFFull

// order-preserving f32 -> u32 map (monotone, injective; finite inputs give
// omap < 2^32, so packed keys < 2^42 and MAXKEY is a safe removal marker)
__device__ __forceinline__ unsigned omap(float v) {
    unsigned u = __float_as_uint(v);
    return (u & 0x80000000u) ? ~u : (u | 0x80000000u);
}
// key = (val asc, row asc); u64 min == lexicographic min
__device__ __forceinline__ unsigned long long packkey(float v, int r) {
    return ((unsigned long long)omap(v) << 10) | (unsigned)r;
}

// ---------------------------------------------------------------------------
// Kernel A: cost matrix + fused per-column min. Grid (225, 64): block
// (s, b) = rows 4s..4s+3 of batch b (900 = 225*4, never crosses batches).
// One wave per row; after computing its 64 costs the block LDS-reduces the
// 4 per-row keys per column and wave 0 atomicMin's into ws[b][m].
// ---------------------------------------------------------------------------
__global__ __launch_bounds__(256) void cost_colmin_kernel(
    const float* __restrict__ logits,   // [B,N,C]
    const float* __restrict__ pboxes,   // [B,N,4] cxcywh
    const int*   __restrict__ labels,   // [B,M]
    const float* __restrict__ tboxes,   // [B,M,4] cxcywh
    float* __restrict__ cost,           // [B,N,M]
    unsigned long long* __restrict__ ws)// [B,M] column-min keys (pre-set MAXKEY)
{
    const int wv   = threadIdx.x >> 6;
    const int lane = threadIdx.x & 63;
    const int b    = blockIdx.y;
    const int row  = blockIdx.x * 4 + wv;
    const int wid  = b * NN + row;

    const float* lrow = logits + (size_t)wid * CC;
    const int L = labels[b * MM + lane];
    const float gl = lrow[L];

    float reg[6];
#pragma unroll
    for (int i = 0; i < 6; ++i) {
        int idx = lane + i * 64;
        reg[i] = (idx < CC) ? lrow[idx] : -INFINITY;
    }
    float mx = reg[0];
#pragma unroll
    for (int i = 1; i < 6; ++i) mx = fmaxf(mx, reg[i]);
#pragma unroll
    for (int off = 32; off; off >>= 1) mx = fmaxf(mx, __shfl_xor(mx, off));

    float se = 0.0f;
#pragma unroll
    for (int i = 0; i < 6; ++i) se += expf(reg[i] - mx);  // expf(-inf)=0
#pragma unroll
    for (int off = 32; off; off >>= 1) se += __shfl_xor(se, off);

    const float cclass = -(expf(gl - mx) / se);

    const float4 pb = *(const float4*)(pboxes + (size_t)wid * 4);
    const float4 tb = *(const float4*)(tboxes + ((size_t)b * MM + lane) * 4);

    const float l1 = fabsf(pb.x - tb.x) + fabsf(pb.y - tb.y) +
                     fabsf(pb.z - tb.z) + fabsf(pb.w - tb.w);

    const float px0 = pb.x - 0.5f * pb.z, py0 = pb.y - 0.5f * pb.w;
    const float px1 = pb.x + 0.5f * pb.z, py1 = pb.y + 0.5f * pb.w;
    const float tx0 = tb.x - 0.5f * tb.z, ty0 = tb.y - 0.5f * tb.w;
    const float tx1 = tb.x + 0.5f * tb.z, ty1 = tb.y + 0.5f * tb.w;

    const float ltx = fmaxf(px0, tx0), lty = fmaxf(py0, ty0);
    const float rbx = fminf(px1, tx1), rby = fminf(py1, ty1);
    const float iw = fmaxf(rbx - ltx, 0.0f), ih = fmaxf(rby - lty, 0.0f);
    const float inter = iw * ih;
    const float a1 = (px1 - px0) * (py1 - py0);
    const float a2 = (tx1 - tx0) * (ty1 - ty0);
    const float uni = a1 + a2 - inter;
    const float iou = inter / (uni + EPSV);
    const float ex0 = fminf(px0, tx0), ey0 = fminf(py0, ty0);
    const float ex1 = fmaxf(px1, tx1), ey1 = fmaxf(py1, ty1);
    const float ae = (ex1 - ex0) * (ey1 - ey0);
    const float giou = iou - (ae - uni) / (ae + EPSV);

    const float c = 1.0f * cclass + 5.0f * l1 + 2.0f * (-giou);
    cost[(size_t)wid * MM + lane] = c;

    // ---- fused column-min: block-reduce 4 rows, one atomicMin per column ----
    __shared__ unsigned long long part[4][MM];
    part[wv][lane] = packkey(c, row);
    __syncthreads();
    if (threadIdx.x < MM) {
        unsigned long long k0 = part[0][threadIdx.x];
        unsigned long long k1 = part[1][threadIdx.x];
        unsigned long long k2 = part[2][threadIdx.x];
        unsigned long long k3 = part[3][threadIdx.x];
        k0 = (k1 < k0) ? k1 : k0;
        k2 = (k3 < k2) ? k3 : k2;
        k0 = (k2 < k0) ? k2 : k0;
        atomicMin(&ws[(size_t)b * MM + threadIdx.x], k0);
    }
}

// ---------------------------------------------------------------------------
// Kernel B: greedy selection, one wave per batch. Lane m owns column m's
// cached (min val, argmin row) key. Column removal = kill lane's key (free).
// Row removal invalidates a column cache with prob ~1/live_rows -> expected
// ~5 cooperative rescans total per batch. Invariant: every live column's key
// is the true min over live rows, so the wave-min of keys is the global min.
// Tie-break = (val asc, row asc via packed key, col asc via ballot+ffs) ==
// jnp.argmin first-flat-index. Hard masking == reference's +1e9 soft mask.
// Row liveness: lane l keeps a 15-bit register bitmap for rows r == l (mod 64).
// ---------------------------------------------------------------------------
__global__ __launch_bounds__(64) void greedy_kernel(
    const float* __restrict__ cost,                  // [B,N,M]
    const unsigned long long* __restrict__ ws,       // [B,M] final col-min keys
    float* __restrict__ outP,                        // [B,K]
    float* __restrict__ outT)                        // [B,K]
{
    const int b    = blockIdx.x;
    const int lane = threadIdx.x;       // == column index
    const float* cb = cost + (size_t)b * NN * MM;

    unsigned long long mykey = ws[(size_t)b * MM + lane];

    unsigned deadbits = 0;              // rows l+64j removed, bit j
    int selp = 0, selt = 0;

#pragma unroll 1
    for (int it = 0; it < KK; ++it) {
        // wave-wide u64 min of live column keys
        unsigned long long mn = mykey;
#pragma unroll
        for (int off = 32; off; off >>= 1) {
            unsigned long long o = __shfl_xor(mn, off);
            mn = (o < mn) ? o : mn;
        }
        const unsigned long long eq = __ballot(mykey == mn);
        const int c = __ffsll((long long)eq) - 1;   // smallest col among ties
        const int r = (int)(mn & 1023u);

        if (lane == it) { selp = r; selt = c; }
        if (lane == c) mykey = MAXKEY;                      // column removed
        if (lane == (r & 63)) deadbits |= 1u << (r >> 6);   // row removed

        // live columns whose cached argmin row was just removed (rare)
        unsigned long long pend =
            __ballot(mykey != MAXKEY && (int)(mykey & 1023u) == r);
#pragma unroll 1
        while (pend) {
            const int pc = __ffsll((long long)pend) - 1;
            pend &= pend - 1;
            // all 64 lanes cooperate: lane covers rows lane+64j
            unsigned long long best = MAXKEY;
#pragma unroll
            for (int j = 0; j < 15; ++j) {
                const int rr = lane + 64 * j;
                if (rr < NN && !((deadbits >> j) & 1u)) {
                    unsigned long long k = packkey(cb[rr * MM + pc], rr);
                    best = (k < best) ? k : best;
                }
            }
#pragma unroll
            for (int off = 32; off; off >>= 1) {
                unsigned long long o = __shfl_xor(best, off);
                best = (o < best) ? o : best;
            }
            if (lane == pc) mykey = best;   // >=1 live row always remains
        }
    }

    outP[b * KK + lane] = (float)selp;
    outT[b * KK + lane] = (float)selt;
}

// ---------------------------------------------------------------------------
extern "C" void kernel_launch(void* const* d_in, const int* in_sizes, int n_in,
                              void* d_out, int out_size, void* d_ws, size_t ws_size,
                              hipStream_t stream) {
    const float* pred_logits = (const float*)d_in[0];  // [64,900,365]
    const float* pred_boxes  = (const float*)d_in[1];  // [64,900,4]
    const int*   tgt_labels  = (const int*)d_in[2];    // [64,64]
    const float* tgt_boxes   = (const float*)d_in[3];  // [64,64,4]

    float* cost = (float*)d_out;                       // [64,900,64]
    float* outP = cost + (size_t)BB * NN * MM;         // [64,64]
    float* outT = outP + (size_t)BB * KK;              // [64,64]
    unsigned long long* wskeys = (unsigned long long*)d_ws;  // 32 KB used

    // ws[b][m] = MAXKEY (0xFF fill) — graph-legal async memset node
    hipMemsetAsync(wskeys, 0xFF, (size_t)BB * MM * sizeof(unsigned long long),
                   stream);

    cost_colmin_kernel<<<dim3(NN / 4, BB), 256, 0, stream>>>(
        pred_logits, pred_boxes, tgt_labels, tgt_boxes, cost, wskeys);

    greedy_kernel<<<BB, 64, 0, stream>>>(cost, wskeys, outP, outT);
}

// Round 14
// 186.413 us; speedup vs baseline: 7.7936x; 1.0076x over previous
//
#include <hip/hip_runtime.h>
#include <hip/hip_bf16.h>
#include <math.h>

// Problem constants (match reference setup_inputs)
#define BB 64
#define NN 900
#define CC 365
#define MM 64
#define KK 64
#define EPSV 1e-6f
#define MAXKEY 0xFFFFFFFFFFFFFFFFull

// order-preserving f32 -> u32 map (monotone, injective; finite inputs give
// omap < 0xFFFFFFFF, so 0xFFFFFFFF is a safe "dead" sentinel after >>10)
__device__ __forceinline__ unsigned omap(float v) {
    unsigned u = __float_as_uint(v);
    return (u & 0x80000000u) ? ~u : (u | 0x80000000u);
}
// key = (val asc, row asc); u64 min == lexicographic min
__device__ __forceinline__ unsigned long long packkey(float v, int r) {
    return ((unsigned long long)omap(v) << 10) | (unsigned)r;
}

__device__ __forceinline__ unsigned wave_min_u32(unsigned v) {
#pragma unroll
    for (int off = 32; off; off >>= 1) {
        unsigned o = (unsigned)__shfl_xor((int)v, off);
        v = (o < v) ? o : v;
    }
    return v;
}

// ---------------------------------------------------------------------------
// Kernel A: cost matrix + fused per-column min. Grid (225, 64): block
// (s, b) = rows 4s..4s+3 of batch b. One wave per row; block LDS-reduces the
// 4 per-row keys per column and does one atomicMin per column into ws[b][m].
// ---------------------------------------------------------------------------
__global__ __launch_bounds__(256) void cost_colmin_kernel(
    const float* __restrict__ logits,   // [B,N,C]
    const float* __restrict__ pboxes,   // [B,N,4] cxcywh
    const int*   __restrict__ labels,   // [B,M]
    const float* __restrict__ tboxes,   // [B,M,4] cxcywh
    float* __restrict__ cost,           // [B,N,M]
    unsigned long long* __restrict__ ws)// [B,M] column-min keys (pre-set MAXKEY)
{
    const int wv   = threadIdx.x >> 6;
    const int lane = threadIdx.x & 63;
    const int b    = blockIdx.y;
    const int row  = blockIdx.x * 4 + wv;
    const int wid  = b * NN + row;

    const float* lrow = logits + (size_t)wid * CC;
    const int L = labels[b * MM + lane];
    const float gl = lrow[L];

    float reg[6];
#pragma unroll
    for (int i = 0; i < 6; ++i) {
        int idx = lane + i * 64;
        reg[i] = (idx < CC) ? lrow[idx] : -INFINITY;
    }
    float mx = reg[0];
#pragma unroll
    for (int i = 1; i < 6; ++i) mx = fmaxf(mx, reg[i]);
#pragma unroll
    for (int off = 32; off; off >>= 1) mx = fmaxf(mx, __shfl_xor(mx, off));

    float se = 0.0f;
#pragma unroll
    for (int i = 0; i < 6; ++i) se += expf(reg[i] - mx);  // expf(-inf)=0
#pragma unroll
    for (int off = 32; off; off >>= 1) se += __shfl_xor(se, off);

    const float cclass = -(expf(gl - mx) / se);

    const float4 pb = *(const float4*)(pboxes + (size_t)wid * 4);
    const float4 tb = *(const float4*)(tboxes + ((size_t)b * MM + lane) * 4);

    const float l1 = fabsf(pb.x - tb.x) + fabsf(pb.y - tb.y) +
                     fabsf(pb.z - tb.z) + fabsf(pb.w - tb.w);

    const float px0 = pb.x - 0.5f * pb.z, py0 = pb.y - 0.5f * pb.w;
    const float px1 = pb.x + 0.5f * pb.z, py1 = pb.y + 0.5f * pb.w;
    const float tx0 = tb.x - 0.5f * tb.z, ty0 = tb.y - 0.5f * tb.w;
    const float tx1 = tb.x + 0.5f * tb.z, ty1 = tb.y + 0.5f * tb.w;

    const float ltx = fmaxf(px0, tx0), lty = fmaxf(py0, ty0);
    const float rbx = fminf(px1, tx1), rby = fminf(py1, ty1);
    const float iw = fmaxf(rbx - ltx, 0.0f), ih = fmaxf(rby - lty, 0.0f);
    const float inter = iw * ih;
    const float a1 = (px1 - px0) * (py1 - py0);
    const float a2 = (tx1 - tx0) * (ty1 - ty0);
    const float uni = a1 + a2 - inter;
    const float iou = inter / (uni + EPSV);
    const float ex0 = fminf(px0, tx0), ey0 = fminf(py0, ty0);
    const float ex1 = fmaxf(px1, tx1), ey1 = fmaxf(py1, ty1);
    const float ae = (ex1 - ex0) * (ey1 - ey0);
    const float giou = iou - (ae - uni) / (ae + EPSV);

    const float c = 1.0f * cclass + 5.0f * l1 + 2.0f * (-giou);
    cost[(size_t)wid * MM + lane] = c;

    // ---- fused column-min: block-reduce 4 rows, one atomicMin per column ----
    __shared__ unsigned long long part[4][MM];
    part[wv][lane] = packkey(c, row);
    __syncthreads();
    if (threadIdx.x < MM) {
        unsigned long long k0 = part[0][threadIdx.x];
        unsigned long long k1 = part[1][threadIdx.x];
        unsigned long long k2 = part[2][threadIdx.x];
        unsigned long long k3 = part[3][threadIdx.x];
        k0 = (k1 < k0) ? k1 : k0;
        k2 = (k3 < k2) ? k3 : k2;
        k0 = (k2 < k0) ? k2 : k0;
        atomicMin(&ws[(size_t)b * MM + threadIdx.x], k0);
    }
}

// ---------------------------------------------------------------------------
// Kernel B: greedy selection, one wave per batch. Lane m owns column m's
// cached (min val, argmin row) key. Per iteration: 32-bit value butterfly +
// ballot; unique-min fast path broadcasts the row via v_readlane (no LDS
// pipe); the tie path does a second 32-bit butterfly on (row<<6|col), which
// reproduces the exact (val,row,col) = jnp.argmin flat-index order.
// Rescans (cached argmin row removed) are cooperative over all 64 lanes.
// ---------------------------------------------------------------------------
__global__ __launch_bounds__(64) void greedy_kernel(
    const float* __restrict__ cost,                  // [B,N,M]
    const unsigned long long* __restrict__ ws,       // [B,M] final col-min keys
    float* __restrict__ outP,                        // [B,K]
    float* __restrict__ outT)                        // [B,K]
{
    const int b    = blockIdx.x;
    const int lane = threadIdx.x;       // == column index
    const float* cb = cost + (size_t)b * NN * MM;

    unsigned long long mykey = ws[(size_t)b * MM + lane];

    unsigned deadbits = 0;              // rows l+64j removed, bit j
    int selp = 0, selt = 0;

#pragma unroll 1
    for (int it = 0; it < KK; ++it) {
        // value-only wave min (dead columns carry 0xFFFFFFFF, unreachable
        // by finite costs)
        const unsigned val32 = (unsigned)(mykey >> 10);
        const unsigned mv = wave_min_u32(val32);
        const unsigned long long eq = __ballot(val32 == mv);
        int r, c;
        if (__popcll(eq) == 1) {         // unique min column (common case)
            c = __ffsll((long long)eq) - 1;
            r = __builtin_amdgcn_readlane((int)(mykey & 1023u), c);
        } else {                          // exact (row, col) tie-break
            unsigned rc = (val32 == mv)
                ? ((((unsigned)(mykey & 1023u)) << 6) | (unsigned)lane)
                : 0xFFFFFFFFu;
            const unsigned mrc = wave_min_u32(rc);
            r = (int)(mrc >> 6);
            c = (int)(mrc & 63u);
        }

        if (lane == it) { selp = r; selt = c; }
        if (lane == c) mykey = MAXKEY;                      // column removed
        if (lane == (r & 63)) deadbits |= 1u << (r >> 6);   // row removed

        // live columns whose cached argmin row was just removed (rare)
        unsigned long long pend =
            __ballot(mykey != MAXKEY && (int)(mykey & 1023u) == r);
#pragma unroll 1
        while (pend) {
            const int pc = __ffsll((long long)pend) - 1;
            pend &= pend - 1;
            // all 64 lanes cooperate: lane covers rows lane+64j
            unsigned long long best = MAXKEY;
#pragma unroll
            for (int j = 0; j < 15; ++j) {
                const int rr = lane + 64 * j;
                if (rr < NN && !((deadbits >> j) & 1u)) {
                    unsigned long long k = packkey(cb[rr * MM + pc], rr);
                    best = (k < best) ? k : best;
                }
            }
            const unsigned bval = (unsigned)(best >> 10);
            const unsigned mv2 = wave_min_u32(bval);
            const unsigned long long eq2 = __ballot(bval == mv2);
            unsigned wr;
            if (__popcll(eq2) == 1) {
                const int wl = __ffsll((long long)eq2) - 1;
                wr = (unsigned)__builtin_amdgcn_readlane(
                         (int)(best & 1023u), wl);
            } else {
                unsigned rr2 = (bval == mv2) ? (unsigned)(best & 1023u)
                                             : 0xFFFFFFFFu;
                wr = wave_min_u32(rr2);
            }
            if (lane == pc)
                mykey = ((unsigned long long)mv2 << 10) | wr;
        }
    }

    outP[b * KK + lane] = (float)selp;
    outT[b * KK + lane] = (float)selt;
}

// ---------------------------------------------------------------------------
extern "C" void kernel_launch(void* const* d_in, const int* in_sizes, int n_in,
                              void* d_out, int out_size, void* d_ws, size_t ws_size,
                              hipStream_t stream) {
    const float* pred_logits = (const float*)d_in[0];  // [64,900,365]
    const float* pred_boxes  = (const float*)d_in[1];  // [64,900,4]
    const int*   tgt_labels  = (const int*)d_in[2];    // [64,64]
    const float* tgt_boxes   = (const float*)d_in[3];  // [64,64,4]

    float* cost = (float*)d_out;                       // [64,900,64]
    float* outP = cost + (size_t)BB * NN * MM;         // [64,64]
    float* outT = outP + (size_t)BB * KK;              // [64,64]
    unsigned long long* wskeys = (unsigned long long*)d_ws;  // 32 KB used

    // ws[b][m] = MAXKEY (0xFF fill) — graph-legal async memset node
    hipMemsetAsync(wskeys, 0xFF, (size_t)BB * MM * sizeof(unsigned long long),
                   stream);

    cost_colmin_kernel<<<dim3(NN / 4, BB), 256, 0, stream>>>(
        pred_logits, pred_boxes, tgt_labels, tgt_boxes, cost, wskeys);

    greedy_kernel<<<BB, 64, 0, stream>>>(cost, wskeys, outP, outT);
}